// Round 7
// baseline (204.392 us; speedup 1.0000x reference)
//
#include <hip/hip_runtime.h>

// ElectronGNN on MI355X (gfx950).  Inputs float32, output float32.
// Round 15: K-split wave pairs — break the 2048-wave invariant.
//   Decomposition: each batch = 4 row-tiles x 2 K-halves = 8 waves.
//   half-0 (waves 0-3): zpass(0)->zstA, x@W0, zs@W1        (128 MFMAs, caches aS only)
//   half-1 (waves 4-7): zpass(1)->zstB, za@W2, Y->zn, zn@W3 (160 MFMAs, caches aA only)
//   Partial upd[8] reconciled via 16KB LDS exchange OVERLAID on consumed
//   zstA/zstB (zero extra LDS), 2 barriers/layer.  xr dropped from regs
//   (old x re-read from xb at epilogue).  Peak live ~116 VGPR < 128 cap.
//   512 blocks x 512 threads, (512,2): LDS 65,792B x2 blocks/CU = 131.6KB
//   => 16 waves/CU = 4 waves/SIMD (was 2) — the first real TLP doubling.
//   Falsifier: FETCH_SIZE must stay <8MB (no spill).
// z B-frags: per-lane v_pk_mul_f16 recompute; wp from LDS-packed weP (r14).
// d_ws: 491,520 B (r7-proven size, unchanged).

typedef unsigned short u16;
typedef unsigned int u32;
typedef __attribute__((ext_vector_type(8))) short short8;
typedef __attribute__((ext_vector_type(4))) float f32x4;
typedef __attribute__((ext_vector_type(4))) u32 u32x4;
typedef _Float16 h2 __attribute__((ext_vector_type(2)));

__device__ __forceinline__ u16 f2h(float f){ return __builtin_bit_cast(u16, (_Float16)f); }
__device__ __forceinline__ float h2f(u16 a){ return (float)__builtin_bit_cast(_Float16, a); }

__device__ __forceinline__ short8 rbf8(float dd){
  short8 a;
#pragma unroll
  for (int f = 0; f < 8; f++){
    float u = dd - (4.0f/7.0f)*(float)f;
    a[f] = (short)f2h(__expf(-u*u));
  }
  return a;
}

// ---------------- prep: frag-linear weight slabs (r7-proven, unchanged) ----------------
__global__ __launch_bounds__(256) void gnn_prep(
    const float* __restrict__ w_up, const float* __restrict__ we_ne,
    const float* __restrict__ embed, const int* __restrict__ atypes,
    u16* __restrict__ wsegs){
  __shared__ u16 lw[16384];
  const int blk = blockIdx.x;          // l*5 + seg
  const int l = blk / 5, seg = blk % 5;
  const int tid = threadIdx.x;
  if (seg < 4){
    const float* src = w_up + (l*512 + seg*128)*128;
#pragma unroll
    for (int mm = 0; mm < 16; mm++){
      int idx = mm*1024 + tid*4;
      float4 v = *(const float4*)(src + idx);
      lw[idx+0] = f2h(v.x); lw[idx+1] = f2h(v.y);
      lw[idx+2] = f2h(v.z); lw[idx+3] = f2h(v.w);
    }
  } else {
#pragma unroll
    for (int mm = 0; mm < 16; mm++){
      int idx = mm*1024 + tid*4;
      int k = idx >> 7, dout = idx & 127;
      int n = k >> 3, f = k & 7;
      float4 ye = *(const float4*)(embed + atypes[n]*128 + dout);
      float4 wn = *(const float4*)(we_ne + (l*8 + f)*128 + dout);
      lw[idx+0] = f2h(ye.x*wn.x); lw[idx+1] = f2h(ye.y*wn.y);
      lw[idx+2] = f2h(ye.z*wn.z); lw[idx+3] = f2h(ye.w*wn.w);
    }
  }
  __syncthreads();
  u16* dst = wsegs + blk*16384;
  const int col = tid & 15, q = (tid >> 4) & 3;
#pragma unroll
  for (int m = 0; m < 8; m++){
    int slot = m*4 + (tid >> 6);
    int c = slot >> 3, nt = slot & 7;
    int kbase = c*32 + q*8;
    int dout = nt*16 + col;
    short8 vv;
#pragma unroll
    for (int jj = 0; jj < 8; jj++) vv[jj] = (short)lw[(kbase+jj)*128 + dout];
    *(short8*)(dst + m*2048 + tid*8) = vv;
  }
}

// ---------------- main ----------------
__global__ __launch_bounds__(512, 2) void gnn_main(
    const float* __restrict__ r_g, const float* __restrict__ R_g,
    const float* __restrict__ weS_g, const float* __restrict__ weA_g,
    const float* __restrict__ bup_g,
    const u16* __restrict__ wsegs,
    float* __restrict__ out)
{
  extern __shared__ __attribute__((aligned(16))) u16 lds[];
  u16* const xb   = lds;                    // [64][136]
  u16* const zstA = lds + 8704;             // [64][136] half-0 rows (zs), later exA
  u16* const zstB = lds + 17408;            // [64][136] half-1 rows (za/zn), later exB
  float* const rs = (float*)(lds + 26112);  // [64][4] electron positions
  float* const Rs = rs + 256;               // [16][4] nuclei positions
  u32* const weP  = (u32*)(lds + 26752);    // [(l*2+pass)*4+p][128] h2-packed weS/weA
  float* const exA = (float*)zstA;          // [64][68] f32 overlay: half-0's nt4-7 partial
  float* const exB = (float*)zstB;          // [64][68] f32 overlay: half-1's nt0-3 partial

  const int tid  = threadIdx.x;
  const int lane = tid & 63;
  const int w    = tid >> 6;            // 0..7
  const int half = w >> 2;              // K-half 0/1
  const int wq   = w & 3;               // row-tile 0..3
  const int b    = blockIdx.x;          // one batch per block
  const int col  = lane & 15;
  const int q    = lane >> 4;
  const int i0   = wq * 16;
  const int sp   = wq >> 1;             // spin group of rows
  const int mrow = i0 + col;
  const int loff = (q*16 + col) * 8;

  // full-width GEMM: K=128 (4 chunks), N=128 (8 tiles).
  // A from row-major LDS; B direct from global wseg (L2-hot, coalesced dwordx4).
  auto gemm_seg = [&](const u16* wseg_g, const u16* arows, f32x4* acc){
#pragma unroll
    for (int c = 0; c < 4; c++){
      short8 a = *(const short8*)(arows + mrow*136 + c*32 + (q<<3));
#pragma unroll
      for (int nt = 0; nt < 8; nt++){
        short8 bf = *(const short8*)(wseg_g + c*4096 + nt*512 + loff);
        acc[nt] = __builtin_amdgcn_mfma_f32_16x16x32_f16(a, bf, acc[nt], 0, 0, 0);
      }
    }
  };

  // ---------------- init: positions, weP pack, per-half A-frag cache, x init ----------------
  short8 aC[8];            // half 0: aS (self-zeroed); half 1: aA
  float dN[4];             // half 1 only
  float px0, px1, px2;
  {
    if (tid < 64){
#pragma unroll
      for (int k = 0; k < 3; k++) rs[tid*4+k] = r_g[(b*64+tid)*3 + k];
    } else if (tid < 80){
      int n = tid - 64;
#pragma unroll
      for (int k = 0; k < 3; k++) Rs[n*4+k] = R_g[(b*16+n)*3 + k];
    }
    // pack weS/weA -> LDS h2 pairs: weP[((l*2+pass)*4+p)*128 + d]
#pragma unroll
    for (int e0 = 0; e0 < 3072; e0 += 512){
      int e = e0 + tid;
      int d = e & 127, p = (e >> 7) & 3, ps = (e >> 9) & 1, ll = e >> 10;
      const float* src = ps ? weA_g : weS_g;
      h2 t;
      t[0] = (_Float16)src[(ll*8 + 2*p  )*128 + d];
      t[1] = (_Float16)src[(ll*8 + 2*p+1)*128 + d];
      weP[((ll*2+ps)*4 + p)*128 + d] = __builtin_bit_cast(u32, t);
    }
    __syncthreads();
    px0 = rs[mrow*4]; px1 = rs[mrow*4+1]; px2 = rs[mrow*4+2];
    if (half == 0){
#pragma unroll
      for (int c = 0; c < 8; c++){
        int j = 32*sp + 4*c + q;
        float dx = px0-rs[j*4], dy = px1-rs[j*4+1], dz = px2-rs[j*4+2];
        aC[c] = rbf8(sqrtf(dx*dx + dy*dy + dz*dz + 1e-12f));
        if (j == mrow) aC[c] = (short8)0;           // no self-interaction
      }
    } else {
#pragma unroll
      for (int c = 0; c < 8; c++){
        int j = 32*(1-sp) + 4*c + q;
        float dx = px0-rs[j*4], dy = px1-rs[j*4+1], dz = px2-rs[j*4+2];
        aC[c] = rbf8(sqrtf(dx*dx + dy*dy + dz*dz + 1e-12f));
      }
#pragma unroll
      for (int c = 0; c < 4; c++){
        int n = 4*c + q;
        float dx = px0-Rs[n*4], dy = px1-Rs[n*4+1], dz = px2-Rs[n*4+2];
        dN[c] = sqrtf(dx*dx + dy*dy + dz*dz + 1e-12f);
      }
    }
    {
      int i = tid >> 3, nb = (tid & 7)*2;          // 512 threads: 2 cells each
      float y0 = rs[i*4], y1 = rs[i*4+1], y2 = rs[i*4+2];
#pragma unroll
      for (int nn = 0; nn < 2; nn++){
        int n = nb + nn;
        float dx = y0-Rs[n*4], dy = y1-Rs[n*4+1], dz = y2-Rs[n*4+2];
        float dd = sqrtf(dx*dx + dy*dy + dz*dz + 1e-12f);
        *(short8*)&xb[i*136 + n*8] = rbf8(dd);
      }
    }
    __syncthreads();       // xb + weP visible to all waves
  }

  const f32x4 vzero = {0.f, 0.f, 0.f, 0.f};

#pragma unroll 1
  for (int l = 0; l < 3; l++){
    const u16* slab = wsegs + l*81920;

    f32x4 upd[8];
#pragma unroll
    for (int nt = 0; nt < 8; nt++) upd[nt] = vzero;

    // z-production for this wave's K-half; A-frags from aC cache; wp from weP.
    auto zpass = [&](int pass, u16* zdst){
      const int jb0 = pass ? 32*(1-sp) : 32*sp;
      const u32* wbase = weP + ((l*2 + pass)*4)*128;
      f32x4 zacc[8];
#pragma unroll
      for (int nt = 0; nt < 8; nt++) zacc[nt] = vzero;
#pragma unroll
      for (int nt = 0; nt < 8; nt++){
        h2 wp[4];
#pragma unroll
        for (int p = 0; p < 4; p++)
          wp[p] = __builtin_bit_cast(h2, wbase[p*128 + nt*16 + col]);
        u16 xv[8];
#pragma unroll
        for (int c = 0; c < 8; c++) xv[c] = xb[(jb0 + 4*c + q)*136 + nt*16 + col];
#pragma unroll
        for (int c = 0; c < 8; c++){
          _Float16 xh = __builtin_bit_cast(_Float16, xv[c]);
          h2 xd; xd[0] = xh; xd[1] = xh;
          u32x4 bu;
#pragma unroll
          for (int p = 0; p < 4; p++)
            bu[p] = __builtin_bit_cast(u32, (h2)(xd * wp[p]));
          short8 bf = __builtin_bit_cast(short8, bu);
          zacc[nt] = __builtin_amdgcn_mfma_f32_16x16x32_f16(aC[c], bf, zacc[nt], 0, 0, 0);
        }
      }
      // zdst rows wave-private: same-wave ds_write->ds_read is lgkm-ordered.
#pragma unroll
      for (int nt = 0; nt < 8; nt++)
#pragma unroll
        for (int rr = 0; rr < 4; rr++)
          zdst[(i0 + q*4 + rr)*136 + nt*16 + col] = f2h(zacc[nt][rr]);
    };

    if (half == 0){
      zpass(0, zstA);
      gemm_seg(slab + 0*16384, xb,   upd);   // x  @ W0
      gemm_seg(slab + 1*16384, zstA, upd);   // zs @ W1
    } else {
      zpass(1, zstB);
      gemm_seg(slab + 2*16384, zstB, upd);   // za @ W2
      {                                      // zn from Y seg -> zstB (za consumed)
        const u16* yseg = slab + 4*16384;
        f32x4 zn[8];
#pragma unroll
        for (int nt = 0; nt < 8; nt++) zn[nt] = vzero;
#pragma unroll
        for (int c = 0; c < 4; c++){
          short8 a = rbf8(dN[c]);
#pragma unroll
          for (int nt = 0; nt < 8; nt++){
            short8 bf = *(const short8*)(yseg + c*4096 + nt*512 + loff);
            zn[nt] = __builtin_amdgcn_mfma_f32_16x16x32_f16(a, bf, zn[nt], 0, 0, 0);
          }
        }
#pragma unroll
        for (int nt = 0; nt < 8; nt++)
#pragma unroll
          for (int rr = 0; rr < 4; rr++)
            zstB[(i0 + q*4 + rr)*136 + nt*16 + col] = f2h(zn[nt][rr]);
      }
      gemm_seg(slab + 3*16384, zstB, upd);   // zn @ W3
    }

    // ---- partial-upd exchange (overlay on own consumed zst region) ----
    {
      float* exsend = half ? exB : exA;      // own rows only: race-free pre-barrier
      const int ntoff = half ? 0 : 4;        // half0 sends nt4-7, half1 sends nt0-3
#pragma unroll
      for (int nt = 0; nt < 4; nt++)
#pragma unroll
        for (int rr = 0; rr < 4; rr++)
          exsend[(i0 + q*4 + rr)*68 + nt*16 + col] = upd[ntoff+nt][rr];
    }
    __syncthreads();
    // ---- finalize kept half: add partner partial, bias, tanh, residual ----
    {
      const float* exrecv = half ? exA : exB;
      const int ntk = half ? 4 : 0;          // kept col-tiles
#pragma unroll
      for (int nt = 0; nt < 4; nt++){
        float bupr = bup_g[l*128 + (ntk+nt)*16 + col];
#pragma unroll
        for (int rr = 0; rr < 4; rr++){
          int row = i0 + q*4 + rr;
          float v = upd[ntk+nt][rr] + exrecv[row*68 + nt*16 + col] + bupr;
          float e = __expf(2.0f * v);
          float th = 1.0f - 2.0f * __builtin_amdgcn_rcpf(e + 1.0f);
          float xn = h2f(xb[row*136 + (ntk+nt)*16 + col]) + th;
          if (l < 2) xb[row*136 + (ntk+nt)*16 + col] = f2h(xn);
          else       out[(b*64 + row)*128 + (ntk+nt)*16 + col] = xn;
        }
      }
    }
    if (l < 2) __syncthreads();   // xb fully updated before next layer's reads
  }
}

extern "C" void kernel_launch(void* const* d_in, const int* in_sizes, int n_in,
                              void* d_out, int out_size, void* d_ws, size_t ws_size,
                              hipStream_t stream){
  const float* r     = (const float*)d_in[0];
  const float* R     = (const float*)d_in[1];
  const float* embed = (const float*)d_in[2];
  const float* weS   = (const float*)d_in[3];
  const float* weA   = (const float*)d_in[4];
  const float* weN   = (const float*)d_in[5];
  const float* wup   = (const float*)d_in[6];
  const float* bup   = (const float*)d_in[7];
  const int* atyp    = (const int*)d_in[8];

  u16* wsegs = (u16*)d_ws;                // 3*5*16384 fp16 = 491,520 B (proven size)

  (void)hipFuncSetAttribute((const void*)gnn_main,
                            hipFuncAttributeMaxDynamicSharedMemorySize, 65792);
  gnn_prep<<<15, 256, 0, stream>>>(wup, weN, embed, atyp, wsegs);
  gnn_main<<<512, 512, 65792, stream>>>(r, R, weS, weA, bup, wsegs, (float*)d_out);
}

// Round 9
// 149.171 us; speedup vs baseline: 1.3702x; 1.3702x over previous
//
#include <hip/hip_runtime.h>

// ElectronGNN on MI355X (gfx950).  Inputs float32, output float32.
// Round 17: r16 BUGFIX.  r16's NaN was a staging-coverage bug: 256-thread
//   block with the 512-thread stg lambdas (stg[4], stride 4096) stages only
//   HALF of each 16384-u16 weight segment -> half of wb uninitialized ->
//   garbage f16 -> inf-inf -> NaN.  Restored r9's proven stg[8]/stride-2048
//   (full coverage; tid in [0,256), tid*8 spans [0,2048)).
//   Kept r16's single structural change: Y-seg read DIRECT from L2 in t3
//   (Y used once/layer, only 4 k-chunks); t2 prefetches W3; t3 barrier-free.
//   Barriers 10 -> 8 per layer.  Everything else bit-identical to r9.
//   512 blocks x 256 threads, (256,2), LDS 67,584 B, 2 blocks/CU.
// z B-frags: per-lane v_pk_mul_f16 recompute (r4/r7-proven).  zst wave-private.
// d_ws: 491,520 B (r7-proven size, unchanged).

typedef unsigned short u16;
typedef unsigned int u32;
typedef __attribute__((ext_vector_type(8))) short short8;
typedef __attribute__((ext_vector_type(4))) float f32x4;
typedef __attribute__((ext_vector_type(4))) u32 u32x4;
typedef _Float16 h2 __attribute__((ext_vector_type(2)));

__device__ __forceinline__ u16 f2h(float f){ return __builtin_bit_cast(u16, (_Float16)f); }
__device__ __forceinline__ float h2f(u16 a){ return (float)__builtin_bit_cast(_Float16, a); }

__device__ __forceinline__ short8 rbf8(float dd){
  short8 a;
#pragma unroll
  for (int f = 0; f < 8; f++){
    float u = dd - (4.0f/7.0f)*(float)f;
    a[f] = (short)f2h(__expf(-u*u));
  }
  return a;
}

// ---------------- prep: frag-linear weight slabs (r7-proven, unchanged) ----------------
__global__ __launch_bounds__(256) void gnn_prep(
    const float* __restrict__ w_up, const float* __restrict__ we_ne,
    const float* __restrict__ embed, const int* __restrict__ atypes,
    u16* __restrict__ wsegs){
  __shared__ u16 lw[16384];
  const int blk = blockIdx.x;          // l*5 + seg
  const int l = blk / 5, seg = blk % 5;
  const int tid = threadIdx.x;
  if (seg < 4){
    const float* src = w_up + (l*512 + seg*128)*128;
#pragma unroll
    for (int mm = 0; mm < 16; mm++){
      int idx = mm*1024 + tid*4;
      float4 v = *(const float4*)(src + idx);
      lw[idx+0] = f2h(v.x); lw[idx+1] = f2h(v.y);
      lw[idx+2] = f2h(v.z); lw[idx+3] = f2h(v.w);
    }
  } else {
#pragma unroll
    for (int mm = 0; mm < 16; mm++){
      int idx = mm*1024 + tid*4;
      int k = idx >> 7, dout = idx & 127;
      int n = k >> 3, f = k & 7;
      float4 ye = *(const float4*)(embed + atypes[n]*128 + dout);
      float4 wn = *(const float4*)(we_ne + (l*8 + f)*128 + dout);
      lw[idx+0] = f2h(ye.x*wn.x); lw[idx+1] = f2h(ye.y*wn.y);
      lw[idx+2] = f2h(ye.z*wn.z); lw[idx+3] = f2h(ye.w*wn.w);
    }
  }
  __syncthreads();
  u16* dst = wsegs + blk*16384;
  const int col = tid & 15, q = (tid >> 4) & 3;
#pragma unroll
  for (int m = 0; m < 8; m++){
    int slot = m*4 + (tid >> 6);
    int c = slot >> 3, nt = slot & 7;
    int kbase = c*32 + q*8;
    int dout = nt*16 + col;
    short8 vv;
#pragma unroll
    for (int jj = 0; jj < 8; jj++) vv[jj] = (short)lw[(kbase+jj)*128 + dout];
    *(short8*)(dst + m*2048 + tid*8) = vv;
  }
}

// ---------------- main ----------------
__global__ __launch_bounds__(256, 2) void gnn_main(
    const float* __restrict__ r_g, const float* __restrict__ R_g,
    const float* __restrict__ weS_g, const float* __restrict__ weA_g,
    const float* __restrict__ bup_g,
    const u16* __restrict__ wsegs,
    float* __restrict__ out)
{
  extern __shared__ __attribute__((aligned(16))) u16 lds[];
  u16* const wb  = lds;                 // 16384 u16 (32 KB), single-buffered
  u16* const xb  = lds + 16384;         // [64][136]
  u16* const zst = lds + 25088;         // [64][136]

  const int tid  = threadIdx.x;
  const int lane = tid & 63;
  const int w    = tid >> 6;            // 0..3 (row-tile within batch)
  const int b    = blockIdx.x;          // one batch per block
  const int col  = lane & 15;
  const int q    = lane >> 4;
  const int i0   = w * 16;
  const int sp   = w >> 1;              // spin group of rows
  const int mrow = i0 + col;
  const int loff = (q*16 + col) * 8;

  // 256-thread staging: 8 stripes x (256 thr x 8 u16) = full 16384-u16 segment.
  // (r16 bug: stg[4]/stride-4096 covers only half at 256 threads.)
  u32x4 stg[8];
  auto stg_ld = [&](const u16* src){
#pragma unroll
    for (int m = 0; m < 8; m++) stg[m] = *(const u32x4*)(src + m*2048 + tid*8);
  };
  auto stg_st = [&](u16* dst){
#pragma unroll
    for (int m = 0; m < 8; m++) *(u32x4*)(dst + m*2048 + tid*8) = stg[m];
  };
  // full-width GEMM: K=128 (4 chunks), N=128 (8 tiles), A from row-major LDS
  auto gemm_seg = [&](const u16* wbuf, const u16* arows, f32x4* acc){
#pragma unroll
    for (int c = 0; c < 4; c++){
      short8 a = *(const short8*)(arows + mrow*136 + c*32 + (q<<3));
#pragma unroll
      for (int nt = 0; nt < 8; nt++){
        short8 bf = *(const short8*)(wbuf + c*4096 + nt*512 + loff);
        acc[nt] = __builtin_amdgcn_mfma_f32_16x16x32_f16(a, bf, acc[nt], 0, 0, 0);
      }
    }
  };

  // ---------------- init: positions, distances, cached A-frags, x init ----------------
  short8 aS[8], aA[8];
  float dN[4];
  {
    float* rs = (float*)zst;             // overlay (dead until first zpass)
    float* Rs = rs + 256;
    if (tid < 64){
#pragma unroll
      for (int k = 0; k < 3; k++) rs[tid*4+k] = r_g[(b*64+tid)*3 + k];
    } else if (tid < 80){
      int n = tid - 64;
#pragma unroll
      for (int k = 0; k < 3; k++) Rs[n*4+k] = R_g[(b*16+n)*3 + k];
    }
    __syncthreads();
    {
      float x0 = rs[mrow*4], x1 = rs[mrow*4+1], x2 = rs[mrow*4+2];
#pragma unroll
      for (int c = 0; c < 8; c++){
        int j = 32*sp + 4*c + q;
        float dx = x0-rs[j*4], dy = x1-rs[j*4+1], dz = x2-rs[j*4+2];
        float dd = sqrtf(dx*dx + dy*dy + dz*dz + 1e-12f);
        aS[c] = rbf8(dd);
        if (j == mrow) aS[c] = (short8)0;          // no self-interaction
        j = 32*(1-sp) + 4*c + q;
        dx = x0-rs[j*4]; dy = x1-rs[j*4+1]; dz = x2-rs[j*4+2];
        aA[c] = rbf8(sqrtf(dx*dx + dy*dy + dz*dz + 1e-12f));
      }
#pragma unroll
      for (int c = 0; c < 4; c++){
        int n = 4*c + q;
        float dx = x0-Rs[n*4], dy = x1-Rs[n*4+1], dz = x2-Rs[n*4+2];
        dN[c] = sqrtf(dx*dx + dy*dy + dz*dz + 1e-12f);
      }
    }
    {
      int i = tid >> 2, nb = (tid & 3)*4;          // 256 threads: 4 cells each
      float y0 = rs[i*4], y1 = rs[i*4+1], y2 = rs[i*4+2];
#pragma unroll
      for (int nn = 0; nn < 4; nn++){
        int n = nb + nn;
        float dx = y0-Rs[n*4], dy = y1-Rs[n*4+1], dz = y2-Rs[n*4+2];
        float dd = sqrtf(dx*dx + dy*dy + dz*dz + 1e-12f);
        *(short8*)&xb[i*136 + n*8] = rbf8(dd);
      }
    }
    stg_ld(wsegs + 0);          // L0.W0 -> wb
    stg_st(wb);
    __syncthreads();
  }

  f32x4 xr[8];
#pragma unroll
  for (int nt = 0; nt < 8; nt++)
#pragma unroll
    for (int rr = 0; rr < 4; rr++)
      xr[nt][rr] = h2f(xb[(i0 + q*4 + rr)*136 + nt*16 + col]);

  const f32x4 vzero = {0.f, 0.f, 0.f, 0.f};

#pragma unroll 1
  for (int l = 0; l < 3; l++){
    const u16* slab = wsegs + l*81920;

    f32x4 upd[8];
#pragma unroll
    for (int nt = 0; nt < 8; nt++) upd[nt] = vzero;

    auto zpass = [&](int pass){
      const float* weX = pass ? weA_g : weS_g;
      const int jb0 = pass ? 32*(1-sp) : 32*sp;
      const short8* aF = pass ? aA : aS;
      f32x4 zacc[8];
#pragma unroll
      for (int nt = 0; nt < 8; nt++) zacc[nt] = vzero;
#pragma unroll
      for (int nt = 0; nt < 8; nt++){
        h2 wp[4];
#pragma unroll
        for (int p = 0; p < 4; p++){
          h2 t;
          t[0] = (_Float16)weX[(l*8 + 2*p  )*128 + nt*16 + col];
          t[1] = (_Float16)weX[(l*8 + 2*p+1)*128 + nt*16 + col];
          wp[p] = t;
        }
        u16 xv[8];
#pragma unroll
        for (int c = 0; c < 8; c++) xv[c] = xb[(jb0 + 4*c + q)*136 + nt*16 + col];
#pragma unroll
        for (int c = 0; c < 8; c++){
          _Float16 xh = __builtin_bit_cast(_Float16, xv[c]);
          h2 xd; xd[0] = xh; xd[1] = xh;
          u32x4 bu;
#pragma unroll
          for (int p = 0; p < 4; p++)
            bu[p] = __builtin_bit_cast(u32, (h2)(xd * wp[p]));
          short8 bf = __builtin_bit_cast(short8, bu);
          zacc[nt] = __builtin_amdgcn_mfma_f32_16x16x32_f16(aF[c], bf, zacc[nt], 0, 0, 0);
        }
      }
      // zst rows wave-private: same-wave ds_write -> ds_read is lgkm-ordered.
#pragma unroll
      for (int nt = 0; nt < 8; nt++)
#pragma unroll
        for (int rr = 0; rr < 4; rr++)
          zst[(i0 + q*4 + rr)*136 + nt*16 + col] = f2h(zacc[nt][rr]);
    };

    // ---- t0: prefetch W1, zpass(0), consume W0 (x@W0)
    stg_ld(slab + 1*16384);
    zpass(0);
    gemm_seg(wb, xb, upd);
    __syncthreads();  stg_st(wb);  __syncthreads();
    // ---- t1: prefetch W2, consume W1 (zs@W1)
    stg_ld(slab + 2*16384);
    gemm_seg(wb, zst, upd);
    __syncthreads();  stg_st(wb);  __syncthreads();
    // ---- t2: prefetch W3, zpass(1), consume W2 (za@W2)
    stg_ld(slab + 3*16384);
    zpass(1);
    gemm_seg(wb, zst, upd);
    __syncthreads();  stg_st(wb);  __syncthreads();
    // ---- t3: zn gemm with Y DIRECT from L2 (used once; no stage, NO barriers)
    {
      const u16* yseg = slab + 4*16384;
      f32x4 zn[8];
#pragma unroll
      for (int nt = 0; nt < 8; nt++) zn[nt] = vzero;
#pragma unroll
      for (int c = 0; c < 4; c++){
        short8 a = rbf8(dN[c]);
#pragma unroll
        for (int nt = 0; nt < 8; nt++){
          short8 bf = *(const short8*)(yseg + c*4096 + nt*512 + loff);
          zn[nt] = __builtin_amdgcn_mfma_f32_16x16x32_f16(a, bf, zn[nt], 0, 0, 0);
        }
      }
#pragma unroll
      for (int nt = 0; nt < 8; nt++)
#pragma unroll
        for (int rr = 0; rr < 4; rr++)
          zst[(i0 + q*4 + rr)*136 + nt*16 + col] = f2h(zn[nt][rr]);
    }
    // ---- t4: prefetch next-layer W0, consume W3 (zn@W3), epilogue
    if (l < 2) stg_ld(slab + 81920);
    gemm_seg(wb, zst, upd);
    {
      float bupr[8];
#pragma unroll
      for (int nt = 0; nt < 8; nt++) bupr[nt] = bup_g[l*128 + nt*16 + col];
#pragma unroll
      for (int nt = 0; nt < 8; nt++){
#pragma unroll
        for (int rr = 0; rr < 4; rr++){
          float v = upd[nt][rr] + bupr[nt];
          float e = __expf(2.0f * v);
          float th = 1.0f - 2.0f * __builtin_amdgcn_rcpf(e + 1.0f);
          xr[nt][rr] += th;
        }
      }
    }
    if (l < 2){
#pragma unroll
      for (int nt = 0; nt < 8; nt++)
#pragma unroll
        for (int rr = 0; rr < 4; rr++)
          xb[(i0 + q*4 + rr)*136 + nt*16 + col] = f2h(xr[nt][rr]);
      __syncthreads();  stg_st(wb);  __syncthreads();
    } else {
#pragma unroll
      for (int nt = 0; nt < 8; nt++)
#pragma unroll
        for (int rr = 0; rr < 4; rr++)
          out[(b*64 + i0 + q*4 + rr)*128 + nt*16 + col] = xr[nt][rr];
    }
  }
}

extern "C" void kernel_launch(void* const* d_in, const int* in_sizes, int n_in,
                              void* d_out, int out_size, void* d_ws, size_t ws_size,
                              hipStream_t stream){
  const float* r     = (const float*)d_in[0];
  const float* R     = (const float*)d_in[1];
  const float* embed = (const float*)d_in[2];
  const float* weS   = (const float*)d_in[3];
  const float* weA   = (const float*)d_in[4];
  const float* weN   = (const float*)d_in[5];
  const float* wup   = (const float*)d_in[6];
  const float* bup   = (const float*)d_in[7];
  const int* atyp    = (const int*)d_in[8];

  u16* wsegs = (u16*)d_ws;                // 3*5*16384 fp16 = 491,520 B (proven size)

  (void)hipFuncSetAttribute((const void*)gnn_main,
                            hipFuncAttributeMaxDynamicSharedMemorySize, 67584);
  gnn_prep<<<15, 256, 0, stream>>>(wup, weN, embed, atyp, wsegs);
  gnn_main<<<512, 256, 67584, stream>>>(r, R, weS, weA, bup, wsegs, (float*)d_out);
}